// Round 6
// baseline (320.814 us; speedup 1.0000x reference)
//
#include <hip/hip_runtime.h>
#include <hip/hip_bf16.h>
#include <math.h>

// Problem constants (static config in reference)
#define NT      4096              // B*T
#define DD      1024              // D
#define EE      8                 // experts
#define KK      2                 // top-k
#define CAP     1280              // EXP_CAP
#define CBN     (NT * EE * CAP)   // 41,943,040 elements per big output
#define NROW    (NT * EE)         // 32768 (t,e) rows per section
#define F4ROW   (CAP / 4)         // 320 float4 per row

#define NB      512               // persistent blocks (2/CU co-resident: 2x64KB LDS <= 160KB)
#define NWAVES  (NB * 4)          // 2048 waves
#define RPW     (2 * NROW / NWAVES) // 32 virtual rows per wave

// LDS index swizzle (involution): spreads per-thread contiguous-32 walks
// across all banks.
__device__ __forceinline__ int swz(int j) { return j ^ ((j >> 5) & 31); }

// Device-scope grid barrier: monotonic counter within one replay (counter is
// zeroed by a memset node at graph start).
__device__ __forceinline__ void gridbar(unsigned* cnt, unsigned target) {
    __syncthreads();
    if (threadIdx.x == 0) {
        __hip_atomic_fetch_add(cnt, 1u, __ATOMIC_ACQ_REL, __HIP_MEMORY_SCOPE_AGENT);
        while (__hip_atomic_load(cnt, __ATOMIC_ACQUIRE, __HIP_MEMORY_SCOPE_AGENT) < target)
            __builtin_amdgcn_s_sleep(8);
    }
    __syncthreads();
}

// ---------------------------------------------------------------------------
// One persistent kernel: phase1 logits -> bar -> phase2 rank tables (block 0)
// -> bar -> phase3 streaming writer (prefetched tables, pure store stream).
// ---------------------------------------------------------------------------
__global__ __launch_bounds__(256, 2) void fused_router_kernel(
    const float* __restrict__ x,        // (NT, D)
    const float* __restrict__ w,        // (E, D)
    float* __restrict__ out,
    unsigned* __restrict__ cnt,
    int* __restrict__ e0, int* __restrict__ e1,
    float* __restrict__ p0, float* __restrict__ p1,
    int* __restrict__ sl, float* __restrict__ val)
{
    __shared__ union {
        float wl[EE * DD];                              // 32 KB (phase 1)
        struct { int se[KK * NT]; float sp[KK * NT]; } s2;  // 64 KB (phase 2)
    } u;
    __shared__ unsigned long long wsumA[4], wsumB[4];

    const int tid  = threadIdx.x;
    const int wave = tid >> 6;
    const int lane = tid & 63;

    // ---------------- Phase 1: logits + top-2 + softmax ----------------
    for (int i = tid; i < EE * DD / 4; i += 256)
        reinterpret_cast<float4*>(u.wl)[i] = reinterpret_cast<const float4*>(w)[i];
    __syncthreads();

    const int wid = blockIdx.x * 4 + wave;              // 0..NWAVES-1
    for (int t = wid; t < NT; t += NWAVES) {            // 2 tokens/wave
        const float4* xt = reinterpret_cast<const float4*>(x + (size_t)t * DD);
        float acc[EE];
        #pragma unroll
        for (int e = 0; e < EE; ++e) acc[e] = 0.0f;

        #pragma unroll
        for (int ii = 0; ii < DD / 4 / 64; ++ii) {      // 4 iters
            const int i = ii * 64 + lane;
            const float4 xv = xt[i];
            #pragma unroll
            for (int e = 0; e < EE; ++e) {
                const float4 wv = reinterpret_cast<const float4*>(u.wl + e * DD)[i];
                acc[e] += xv.x * wv.x + xv.y * wv.y + xv.z * wv.z + xv.w * wv.w;
            }
        }

        #pragma unroll
        for (int e = 0; e < EE; ++e) {
            float v = acc[e];
            #pragma unroll
            for (int off = 32; off > 0; off >>= 1) v += __shfl_xor(v, off);
            acc[e] = v;
        }

        if (lane == 0) {
            int b0 = 0; float l0 = acc[0];
            #pragma unroll
            for (int e = 1; e < EE; ++e) { if (acc[e] > l0) { l0 = acc[e]; b0 = e; } }
            int b1 = -1; float l1 = -INFINITY;
            #pragma unroll
            for (int e = 0; e < EE; ++e) { if (e != b0 && acc[e] > l1) { l1 = acc[e]; b1 = e; } }

            const float z  = expf(l1 - l0);             // l1 <= l0
            const float pa = 1.0f / (1.0f + z);
            const float pb = z * pa;

            e0[t] = b0; e1[t] = b1;
            p0[t] = pa; p1[t] = pb;
        }
    }

    gridbar(cnt, NB);                                   // all logits visible

    // ---------------- Phase 2: ordered rank -> tables (block 0) ----------------
    if (blockIdx.x == 0) {
        // init slot table to -1
        int4* sl4 = reinterpret_cast<int4*>(sl);
        const int4 neg = make_int4(-1, -1, -1, -1);
        for (int i = tid; i < NROW / 4; i += 256) sl4[i] = neg;

        // coalesced stage of assignments into LDS
        for (int i = tid; i < NT; i += 256) {
            u.s2.se[swz(i)]      = e0[i];
            u.s2.se[swz(NT + i)] = e1[i];
            u.s2.sp[swz(i)]      = p0[i];
            u.s2.sp[swz(NT + i)] = p1[i];
        }
        __syncthreads();

        const int base = tid * 32;
        unsigned long long ca = 0ull, cb = 0ull;        // experts 0-3 / 4-7, 16b fields
        #pragma unroll
        for (int i = 0; i < 32; ++i) {
            const int e = u.s2.se[swz(base + i)];
            if (e < 4) ca += 1ull << (16 * e);
            else       cb += 1ull << (16 * (e - 4));
        }

        unsigned long long sa = ca, sb = cb;            // intra-wave inclusive scan
        #pragma unroll
        for (int off = 1; off < 64; off <<= 1) {
            const unsigned long long ta = __shfl_up(sa, off);
            const unsigned long long tb = __shfl_up(sb, off);
            if ((tid & 63) >= off) { sa += ta; sb += tb; }
        }
        if ((tid & 63) == 63) { wsumA[wave] = sa; wsumB[wave] = sb; }
        __syncthreads();

        unsigned long long preA = 0ull, preB = 0ull;
        #pragma unroll
        for (int k = 0; k < 4; ++k) {
            if (k < wave) { preA += wsumA[k]; preB += wsumB[k]; }
        }
        unsigned long long ra = preA + sa - ca;         // exclusive prefix
        unsigned long long rb = preB + sb - cb;

        // replay in ascending j order; fill tables
        #pragma unroll
        for (int i = 0; i < 32; ++i) {
            const int j = base + i;
            const int e = u.s2.se[swz(j)];
            int rank;
            if (e < 4) { rank = (int)((ra >> (16 * e)) & 0xFFFF);       ra += 1ull << (16 * e); }
            else       { rank = (int)((rb >> (16 * (e - 4))) & 0xFFFF); rb += 1ull << (16 * (e - 4)); }
            if (rank < CAP) {
                const int t = j & (NT - 1);
                sl[t * EE + e]  = rank;
                val[t * EE + e] = u.s2.sp[swz(j)];
            }
        }

        // used_cap -> out[0..7]
        if (tid < EE) {
            const unsigned long long totA = wsumA[0] + wsumA[1] + wsumA[2] + wsumA[3];
            const unsigned long long totB = wsumB[0] + wsumB[1] + wsumB[2] + wsumB[3];
            const int e = tid;
            const int tot = (e < 4) ? (int)((totA >> (16 * e)) & 0xFFFF)
                                    : (int)((totB >> (16 * (e - 4))) & 0xFFFF);
            out[e] = (float)((tot < CAP) ? tot : CAP);
        }
    }

    gridbar(cnt, 2 * NB);                               // tables visible

    // ---------------- Phase 3: streaming writer, pure store stream ----------------
    // 65536 virtual rows cover [weights | mask] contiguously (stride 1280 f32).
    // Prefetch this wave's 32 (slot,p) pairs with 2 coalesced loads, then the
    // row loop is register-only (readlane broadcast) + back-to-back stores.
    const int gw     = blockIdx.x * 4 + wave;           // 0..2047
    const int vbase  = gw * RPW;                        // first virtual row
    const int rbase  = vbase & (NROW - 1);              // table row base
    const bool ismask = (vbase >= NROW);                // whole chunk in one section

    int   sv = -1; float pv = 0.0f;
    if (lane < RPW) { sv = sl[rbase + lane]; pv = val[rbase + lane]; }

    float4* dst = reinterpret_cast<float4*>(out + 8) + (size_t)vbase * F4ROW;

    #pragma unroll 4
    for (int rr = 0; rr < RPW; ++rr) {
        const int   s = __shfl(sv, rr);                 // wave-uniform broadcast
        const float p = __shfl(pv, rr);
        const bool  on = (s >= 0) && (p != 0.0f);
        const float hv = ismask ? 1.0f : p;

        #pragma unroll
        for (int it = 0; it < 5; ++it) {
            const int f4 = (it << 6) + lane;            // 0..319
            const int c  = f4 << 2;
            float4 v;
            v.x = (on && s == c)     ? hv : 0.0f;
            v.y = (on && s == c + 1) ? hv : 0.0f;
            v.z = (on && s == c + 2) ? hv : 0.0f;
            v.w = (on && s == c + 3) ? hv : 0.0f;
            dst[rr * F4ROW + f4] = v;
        }
    }
}

// ---------------------------------------------------------------------------
extern "C" void kernel_launch(void* const* d_in, const int* in_sizes, int n_in,
                              void* d_out, int out_size, void* d_ws, size_t ws_size,
                              hipStream_t stream) {
    const float* x = (const float*)d_in[0];     // (B,T,D) f32
    const float* w = (const float*)d_in[1];     // (E,D)   f32
    float* out = (float*)d_out;

    char* ws = (char*)d_ws;
    unsigned* cnt = (unsigned*)(ws);                    // 64 B barrier counter
    int*   e0  = (int*)(ws + 1 * 1024);                 // 16 KB
    int*   e1  = (int*)(ws + 17 * 1024);                // 16 KB
    float* p0  = (float*)(ws + 33 * 1024);              // 16 KB
    float* p1  = (float*)(ws + 49 * 1024);              // 16 KB
    int*   sl  = (int*)(ws + 72 * 1024);                // 128 KB (NROW ints)
    float* val = (float*)(ws + 200 * 1024);             // 128 KB (NROW floats)

    // zero the barrier counter each replay (tiny memset node, poison-proof)
    hipMemsetAsync(cnt, 0, 64, stream);

    // single persistent kernel: logits -> bar -> rank tables -> bar -> write
    fused_router_kernel<<<NB, 256, 0, stream>>>(x, w, out, cnt, e0, e1, p0, p1, sl, val);
}

// Round 7
// 85.831 us; speedup vs baseline: 3.7377x; 3.7377x over previous
//
#include <hip/hip_runtime.h>
#include <hip/hip_bf16.h>
#include <math.h>

// Problem constants (static config in reference)
#define NT      4096              // B*T
#define DD      1024              // D
#define EE      8                 // experts
#define KK      2                 // top-k
#define CAP     1280              // EXP_CAP
#define CBN     (NT * EE * CAP)   // 41,943,040 elements per big output

// LDS index swizzle (involution): spreads per-thread contiguous-32 walks
// across all banks.
__device__ __forceinline__ int swz(int j) { return j ^ ((j >> 5) & 31); }

// ---------------------------------------------------------------------------
// K1: router logits + top-2 + softmax(top-2). Wave per token, w in LDS.
// (validated round 2-4, absmax 0)
// ---------------------------------------------------------------------------
__global__ __launch_bounds__(256) void logits_kernel(
    const float* __restrict__ x,        // (NT, D)
    const float* __restrict__ w,        // (E, D)
    int* __restrict__ e0, int* __restrict__ e1,
    float* __restrict__ p0, float* __restrict__ p1)
{
    __shared__ float wl[EE * DD];       // 32 KB

    for (int i = threadIdx.x; i < EE * DD / 4; i += 256)
        reinterpret_cast<float4*>(wl)[i] = reinterpret_cast<const float4*>(w)[i];
    __syncthreads();

    const int wave = threadIdx.x >> 6;
    const int lane = threadIdx.x & 63;
    const int wid  = blockIdx.x * 4 + wave;

    for (int t = wid; t < NT; t += gridDim.x * 4) {
        const float4* xt = reinterpret_cast<const float4*>(x + (size_t)t * DD);
        float acc[EE];
        #pragma unroll
        for (int e = 0; e < EE; ++e) acc[e] = 0.0f;

        #pragma unroll
        for (int ii = 0; ii < DD / 4 / 64; ++ii) {      // 4 iters
            const int i = ii * 64 + lane;
            const float4 xv = xt[i];
            #pragma unroll
            for (int e = 0; e < EE; ++e) {
                const float4 wv = reinterpret_cast<const float4*>(wl + e * DD)[i];
                acc[e] += xv.x * wv.x + xv.y * wv.y + xv.z * wv.z + xv.w * wv.w;
            }
        }

        #pragma unroll
        for (int e = 0; e < EE; ++e) {
            float v = acc[e];
            #pragma unroll
            for (int off = 32; off > 0; off >>= 1) v += __shfl_xor(v, off);
            acc[e] = v;
        }

        if (lane == 0) {
            int b0 = 0; float l0 = acc[0];
            #pragma unroll
            for (int e = 1; e < EE; ++e) { if (acc[e] > l0) { l0 = acc[e]; b0 = e; } }
            int b1 = -1; float l1 = -INFINITY;
            #pragma unroll
            for (int e = 0; e < EE; ++e) { if (e != b0 && acc[e] > l1) { l1 = acc[e]; b1 = e; } }

            const float z  = expf(l1 - l0);     // l1 <= l0
            const float pa = 1.0f / (1.0f + z);
            const float pb = z * pa;

            e0[t] = b0; e1[t] = b1;
            p0[t] = pa; p1[t] = pb;
        }
    }
}

// ---------------------------------------------------------------------------
// K2: fused ordered rank / capacity drop / used_cap / scatter.
// One block, 256 threads. Assignment order j = k*NT + t. LDS-staged inputs,
// 16-bit-packed per-expert counters in 2 x u64, shfl scan + LDS inter-wave
// scan, replay emits the <=16384 scattered stores into the memset-zeroed out.
// (validated round 2, absmax 0)
// ---------------------------------------------------------------------------
__global__ __launch_bounds__(256) void rank_scatter_kernel(
    const int* __restrict__ e0, const int* __restrict__ e1,
    const float* __restrict__ p0, const float* __restrict__ p1,
    float* __restrict__ out)
{
    __shared__ int   se[KK * NT];       // 32 KB, swizzled
    __shared__ float sp[KK * NT];       // 32 KB, swizzled
    __shared__ unsigned long long wsumA[4], wsumB[4];

    const int tid = threadIdx.x;

    // coalesced stage (writes are bank-conflict-free under swz)
    for (int i = tid; i < NT; i += 256) {
        se[swz(i)]      = e0[i];
        se[swz(NT + i)] = e1[i];
        sp[swz(i)]      = p0[i];
        sp[swz(NT + i)] = p1[i];
    }
    __syncthreads();

    const int base = tid * 32;
    unsigned long long ca = 0ull, cb = 0ull;    // experts 0-3 / 4-7, 16b fields
    #pragma unroll
    for (int i = 0; i < 32; ++i) {
        const int e = se[swz(base + i)];
        if (e < 4) ca += 1ull << (16 * e);
        else       cb += 1ull << (16 * (e - 4));
    }

    // intra-wave inclusive scan
    unsigned long long sa = ca, sb = cb;
    #pragma unroll
    for (int off = 1; off < 64; off <<= 1) {
        const unsigned long long ta = __shfl_up(sa, off);
        const unsigned long long tb = __shfl_up(sb, off);
        if ((tid & 63) >= off) { sa += ta; sb += tb; }
    }
    const int wv = tid >> 6;
    if ((tid & 63) == 63) { wsumA[wv] = sa; wsumB[wv] = sb; }
    __syncthreads();

    unsigned long long preA = 0ull, preB = 0ull;
    #pragma unroll
    for (int k = 0; k < 4; ++k) {
        if (k < wv) { preA += wsumA[k]; preB += wsumB[k]; }
    }
    unsigned long long ra = preA + sa - ca;     // exclusive prefix, this thread
    unsigned long long rb = preB + sb - cb;

    // replay in ascending j order + scatter
    #pragma unroll
    for (int i = 0; i < 32; ++i) {
        const int j = base + i;
        const int e = se[swz(j)];
        int rank;
        if (e < 4) { rank = (int)((ra >> (16 * e)) & 0xFFFF);       ra += 1ull << (16 * e); }
        else       { rank = (int)((rb >> (16 * (e - 4))) & 0xFFFF); rb += 1ull << (16 * (e - 4)); }
        if (rank < CAP) {
            const float p = sp[swz(j)];
            if (p != 0.0f) {                    // sec_mask == (cb_weight != 0)
                const int t = j & (NT - 1);
                const size_t idx = (size_t)t * (EE * CAP) + (size_t)e * CAP + (size_t)rank;
                out[8 + idx] = p;
                out[8 + (size_t)CBN + idx] = 1.0f;
            }
        }
    }

    // used_cap
    if (tid < EE) {
        const unsigned long long totA = wsumA[0] + wsumA[1] + wsumA[2] + wsumA[3];
        const unsigned long long totB = wsumB[0] + wsumB[1] + wsumB[2] + wsumB[3];
        const int e = tid;
        const int tot = (e < 4) ? (int)((totA >> (16 * e)) & 0xFFFF)
                                : (int)((totB >> (16 * (e - 4))) & 0xFFFF);
        out[e] = (float)((tot < CAP) ? tot : CAP);
    }
}

// ---------------------------------------------------------------------------
extern "C" void kernel_launch(void* const* d_in, const int* in_sizes, int n_in,
                              void* d_out, int out_size, void* d_ws, size_t ws_size,
                              hipStream_t stream) {
    const float* x = (const float*)d_in[0];     // (B,T,D) f32
    const float* w = (const float*)d_in[1];     // (E,D)   f32
    float* out = (float*)d_out;

    char* ws = (char*)d_ws;
    int*   e0 = (int*)(ws);                     // 16 KB
    int*   e1 = (int*)(ws + 16 * 1024);         // 16 KB
    float* p0 = (float*)(ws + 32 * 1024);       // 16 KB
    float* p1 = (float*)(ws + 48 * 1024);       // 16 KB

    // 1) zero the entire output via the ROCclr fill path (~7 TB/s, ~48 us).
    //    Hand-written fill kernels measured only ~4 TB/s (rounds 2-6).
    hipMemsetAsync(d_out, 0, (size_t)out_size * sizeof(float), stream);

    // 2) router logits + top-2 + softmax (~4 us)
    logits_kernel<<<256, 256, 0, stream>>>(x, w, e0, e1, p0, p1);

    // 3) fused ordered rank + capacity + used_cap + scatter (~6 us, 1 block)
    rank_scatter_kernel<<<1, 256, 0, stream>>>(e0, e1, p0, p1, out);
}

// Round 8
// 79.858 us; speedup vs baseline: 4.0173x; 1.0748x over previous
//
#include <hip/hip_runtime.h>
#include <hip/hip_bf16.h>
#include <math.h>

// Problem constants (static config in reference)
#define NT      4096              // B*T
#define DD      1024              // D
#define EE      8                 // experts
#define KK      2                 // top-k
#define CAP     1280              // EXP_CAP
#define CBN     (NT * EE * CAP)   // 41,943,040 elements per big output

#define K2T     1024              // K2 threads (16 waves, one block)
#define JPT     (KK * NT / K2T)   // 8 assignments per thread

// LDS index swizzle (involution): spreads per-thread contiguous walks
// across banks (<=2-way aliasing for stride-8 and stride-32 walks).
__device__ __forceinline__ int swz(int j) { return j ^ ((j >> 5) & 31); }

// ---------------------------------------------------------------------------
// K1: router logits + top-2 + softmax(top-2). Wave per 2 tokens, w in LDS.
// ---------------------------------------------------------------------------
__global__ __launch_bounds__(256) void logits_kernel(
    const float* __restrict__ x,        // (NT, D)
    const float* __restrict__ w,        // (E, D)
    int* __restrict__ e0, int* __restrict__ e1,
    float* __restrict__ p0, float* __restrict__ p1)
{
    __shared__ float wl[EE * DD];       // 32 KB

    for (int i = threadIdx.x; i < EE * DD / 4; i += 256)
        reinterpret_cast<float4*>(wl)[i] = reinterpret_cast<const float4*>(w)[i];
    __syncthreads();

    const int wave = threadIdx.x >> 6;
    const int lane = threadIdx.x & 63;
    const int wid  = blockIdx.x * 4 + wave;

    for (int t = wid; t < NT; t += gridDim.x * 4) {
        const float4* xt = reinterpret_cast<const float4*>(x + (size_t)t * DD);
        float acc[EE];
        #pragma unroll
        for (int e = 0; e < EE; ++e) acc[e] = 0.0f;

        #pragma unroll
        for (int ii = 0; ii < DD / 4 / 64; ++ii) {      // 4 iters
            const int i = ii * 64 + lane;
            const float4 xv = xt[i];
            #pragma unroll
            for (int e = 0; e < EE; ++e) {
                const float4 wv = reinterpret_cast<const float4*>(wl + e * DD)[i];
                acc[e] += xv.x * wv.x + xv.y * wv.y + xv.z * wv.z + xv.w * wv.w;
            }
        }

        #pragma unroll
        for (int e = 0; e < EE; ++e) {
            float v = acc[e];
            #pragma unroll
            for (int off = 32; off > 0; off >>= 1) v += __shfl_xor(v, off);
            acc[e] = v;
        }

        if (lane == 0) {
            int b0 = 0; float l0 = acc[0];
            #pragma unroll
            for (int e = 1; e < EE; ++e) { if (acc[e] > l0) { l0 = acc[e]; b0 = e; } }
            int b1 = -1; float l1 = -INFINITY;
            #pragma unroll
            for (int e = 0; e < EE; ++e) { if (e != b0 && acc[e] > l1) { l1 = acc[e]; b1 = e; } }

            const float z  = expf(l1 - l0);     // l1 <= l0
            const float pa = 1.0f / (1.0f + z);
            const float pb = z * pa;

            e0[t] = b0; e1[t] = b1;
            p0[t] = pa; p1[t] = pb;
        }
    }
}

// ---------------------------------------------------------------------------
// K2: fused ordered rank / capacity drop / used_cap / scatter.
// One block, 1024 threads (16 waves). Assignment order j = k*NT + t.
// LDS-staged inputs, 16-bit-packed per-expert counters in 2 x u64,
// shfl scan + 16-wave LDS scan, replay (8/thread) emits scattered stores
// into the memset-zeroed output.
// ---------------------------------------------------------------------------
__global__ __launch_bounds__(K2T) void rank_scatter_kernel(
    const int* __restrict__ e0, const int* __restrict__ e1,
    const float* __restrict__ p0, const float* __restrict__ p1,
    float* __restrict__ out)
{
    __shared__ int   se[KK * NT];       // 32 KB, swizzled
    __shared__ float sp[KK * NT];       // 32 KB, swizzled
    __shared__ unsigned long long wsumA[16], wsumB[16];

    const int tid = threadIdx.x;

    // coalesced stage
    #pragma unroll
    for (int k = 0; k < NT / K2T; ++k) {            // 4 iters
        const int i = k * K2T + tid;
        se[swz(i)]      = e0[i];
        se[swz(NT + i)] = e1[i];
        sp[swz(i)]      = p0[i];
        sp[swz(NT + i)] = p1[i];
    }
    __syncthreads();

    const int base = tid * JPT;
    unsigned long long ca = 0ull, cb = 0ull;        // experts 0-3 / 4-7, 16b fields
    #pragma unroll
    for (int i = 0; i < JPT; ++i) {
        const int e = se[swz(base + i)];
        if (e < 4) ca += 1ull << (16 * e);
        else       cb += 1ull << (16 * (e - 4));
    }

    // intra-wave inclusive scan
    unsigned long long sa = ca, sb = cb;
    #pragma unroll
    for (int off = 1; off < 64; off <<= 1) {
        const unsigned long long ta = __shfl_up(sa, off);
        const unsigned long long tb = __shfl_up(sb, off);
        if ((tid & 63) >= off) { sa += ta; sb += tb; }
    }
    const int wv = tid >> 6;                        // 0..15
    if ((tid & 63) == 63) { wsumA[wv] = sa; wsumB[wv] = sb; }
    __syncthreads();

    unsigned long long preA = 0ull, preB = 0ull;
    #pragma unroll
    for (int k = 0; k < 16; ++k) {
        if (k < wv) { preA += wsumA[k]; preB += wsumB[k]; }
    }
    unsigned long long ra = preA + sa - ca;         // exclusive prefix, this thread
    unsigned long long rb = preB + sb - cb;

    // replay in ascending j order + scatter
    #pragma unroll
    for (int i = 0; i < JPT; ++i) {
        const int j = base + i;
        const int e = se[swz(j)];
        int rank;
        if (e < 4) { rank = (int)((ra >> (16 * e)) & 0xFFFF);       ra += 1ull << (16 * e); }
        else       { rank = (int)((rb >> (16 * (e - 4))) & 0xFFFF); rb += 1ull << (16 * (e - 4)); }
        if (rank < CAP) {
            const float p = sp[swz(j)];
            if (p != 0.0f) {                        // sec_mask == (cb_weight != 0)
                const int t = j & (NT - 1);
                const size_t idx = (size_t)t * (EE * CAP) + (size_t)e * CAP + (size_t)rank;
                out[8 + idx] = p;
                out[8 + (size_t)CBN + idx] = 1.0f;
            }
        }
    }

    // used_cap
    if (tid < EE) {
        unsigned long long totA = 0ull, totB = 0ull;
        #pragma unroll
        for (int k = 0; k < 16; ++k) { totA += wsumA[k]; totB += wsumB[k]; }
        const int e = tid;
        const int tot = (e < 4) ? (int)((totA >> (16 * e)) & 0xFFFF)
                                : (int)((totB >> (16 * (e - 4))) & 0xFFFF);
        out[e] = (float)((tot < CAP) ? tot : CAP);
    }
}

// ---------------------------------------------------------------------------
extern "C" void kernel_launch(void* const* d_in, const int* in_sizes, int n_in,
                              void* d_out, int out_size, void* d_ws, size_t ws_size,
                              hipStream_t stream) {
    const float* x = (const float*)d_in[0];     // (B,T,D) f32
    const float* w = (const float*)d_in[1];     // (E,D)   f32
    float* out = (float*)d_out;

    char* ws = (char*)d_ws;
    int*   e0 = (int*)(ws);                     // 16 KB
    int*   e1 = (int*)(ws + 16 * 1024);         // 16 KB
    float* p0 = (float*)(ws + 32 * 1024);       // 16 KB
    float* p1 = (float*)(ws + 48 * 1024);       // 16 KB

    // 1) zero the entire output via the ROCclr fill path (~7 TB/s).
    //    Hand-written fill kernels measured only ~4 TB/s (rounds 2-6).
    hipMemsetAsync(d_out, 0, (size_t)out_size * sizeof(float), stream);

    // 2) router logits + top-2 + softmax (512 blocks: shorter latency tail)
    logits_kernel<<<512, 256, 0, stream>>>(x, w, e0, e1, p0, p1);

    // 3) fused ordered rank + capacity + used_cap + scatter (1 block, 16 waves)
    rank_scatter_kernel<<<1, K2T, 0, stream>>>(e0, e1, p0, p1, out);
}